// Round 1
// baseline (2625.627 us; speedup 1.0000x reference)
//
#include <hip/hip_runtime.h>

#define BATCH 16
#define NPTS 16384
#define MCENT 1024
#define NSAMPLE 32

// ---------------- FPS: one block per batch ----------------
// 1024 threads, 16 points per thread held in registers.
__global__ __launch_bounds__(1024) void fps_kernel(const float* __restrict__ xyz,
                                                   float* __restrict__ cent_out) {
#pragma clang fp contract(off)
    const int b = blockIdx.x;
    const int tid = threadIdx.x;
    const int lane = tid & 63;
    const int wid = tid >> 6;
    const float* xb = xyz + (size_t)b * NPTS * 3;
    float* cb = cent_out + (size_t)b * MCENT * 3;

    float px[16], py[16], pz[16], md[16];
#pragma unroll
    for (int j = 0; j < 16; ++j) {
        int p = j * 1024 + tid;
        px[j] = xb[p * 3 + 0];
        py[j] = xb[p * 3 + 1];
        pz[j] = xb[p * 3 + 2];
        md[j] = 1e10f;
    }

    __shared__ float redv[16];
    __shared__ int   redi[16];
    __shared__ int   cur_sh;

    int cur = 0;  // first selected index is always 0 (scan outputs carry-in)
    for (int m = 0; m < MCENT; ++m) {
        int c = __builtin_amdgcn_readfirstlane(cur);
        // uniform broadcast load of current centroid coords (L1-cached)
        float cx = xb[c * 3 + 0];
        float cy = xb[c * 3 + 1];
        float cz = xb[c * 3 + 2];
        if (tid == 0) {
            cb[m * 3 + 0] = cx;
            cb[m * 3 + 1] = cy;
            cb[m * 3 + 2] = cz;
        }
        // update min-dist + local argmax (ascending index => first-index tiebreak)
        float bv = -1.0f;
        int bi = 0x7fffffff;
#pragma unroll
        for (int j = 0; j < 16; ++j) {
            float dx = px[j] - cx;
            float dy = py[j] - cy;
            float dz = pz[j] - cz;
            float d = dx * dx + dy * dy;
            d = d + dz * dz;                 // ((dx^2+dy^2)+dz^2), no fma
            float nm = fminf(md[j], d);
            md[j] = nm;
            if (nm > bv) { bv = nm; bi = j * 1024 + tid; }
        }
        // wave butterfly argmax, first-index on ties
#pragma unroll
        for (int off = 32; off >= 1; off >>= 1) {
            float ov = __shfl_xor(bv, off);
            int   oi = __shfl_xor(bi, off);
            if (ov > bv || (ov == bv && oi < bi)) { bv = ov; bi = oi; }
        }
        if (lane == 0) { redv[wid] = bv; redi[wid] = bi; }
        __syncthreads();
        if (wid == 0) {
            float v = (lane < 16) ? redv[lane] : -1.0f;
            int   i = (lane < 16) ? redi[lane] : 0x7fffffff;
#pragma unroll
            for (int off = 8; off >= 1; off >>= 1) {
                float ov = __shfl_xor(v, off);
                int   oi = __shfl_xor(i, off);
                if (ov > v || (ov == v && oi < i)) { v = ov; i = oi; }
            }
            if (lane == 0) cur_sh = i;
        }
        __syncthreads();
        cur = cur_sh;
    }
}

// ---------------- Ball query + group: one wave per centroid ----------------
__global__ __launch_bounds__(256) void ballq_kernel(const float* __restrict__ xyz,
                                                    const float* __restrict__ cent,
                                                    float* __restrict__ grouped) {
#pragma clang fp contract(off)
    const int lane = threadIdx.x & 63;
    const int wib = threadIdx.x >> 6;
    const int cid = blockIdx.x * 4 + wib;      // [0, BATCH*MCENT)
    const int b = cid >> 10;                   // MCENT = 1024
    const float* xb = xyz + (size_t)b * NPTS * 3;
    const float* c = cent + (size_t)cid * 3;
    float cx = c[0], cy = c[1], cz = c[2];
    float* g = grouped + (size_t)cid * NSAMPLE * 3;

    // reference compares against float32(double(0.1)*double(0.1)) = 0.00999999977648f
    const float R2 = (float)(0.1 * 0.1);

    int total = 0;
    int first_p = -1;

    for (int p0 = 0; p0 < NPTS && total < NSAMPLE; p0 += 64) {
        int p = p0 + lane;
        float x = xb[p * 3 + 0];
        float y = xb[p * 3 + 1];
        float z = xb[p * 3 + 2];
        float dx = x - cx;
        float dy = y - cy;
        float dz = z - cz;
        float d = dx * dx + dy * dy;
        d = d + dz * dz;
        bool hit = d < R2;
        unsigned long long mask = __ballot(hit);
        if (hit) {
            unsigned int mb = __builtin_amdgcn_mbcnt_lo((unsigned int)mask, 0u);
            mb = __builtin_amdgcn_mbcnt_hi((unsigned int)(mask >> 32), mb);
            int pos = total + (int)mb;          // bits of mask strictly below lane
            if (pos < NSAMPLE) {
                g[pos * 3 + 0] = dx;
                g[pos * 3 + 1] = dy;
                g[pos * 3 + 2] = dz;
            }
        }
        if (first_p < 0 && mask != 0ull) first_p = p0 + __builtin_ctzll(mask);
        total += __popcll(mask);
    }

    int sel = total < NSAMPLE ? total : NSAMPLE;
    if (sel < NSAMPLE) {
        // pad remaining slots with the first hit (guaranteed: centroid itself hits)
        float fx = xb[first_p * 3 + 0] - cx;
        float fy = xb[first_p * 3 + 1] - cy;
        float fz = xb[first_p * 3 + 2] - cz;
        int s = lane;
        if (s >= sel && s < NSAMPLE) {
            g[s * 3 + 0] = fx;
            g[s * 3 + 1] = fy;
            g[s * 3 + 2] = fz;
        }
    }
}

extern "C" void kernel_launch(void* const* d_in, const int* in_sizes, int n_in,
                              void* d_out, int out_size, void* d_ws, size_t ws_size,
                              hipStream_t stream) {
    const float* xyz = (const float*)d_in[0];
    float* out = (float*)d_out;
    float* grouped = out;                                       // [B, M, NSAMPLE, 3]
    float* cent = out + (size_t)BATCH * MCENT * NSAMPLE * 3;    // [B, M, 3]

    fps_kernel<<<BATCH, 1024, 0, stream>>>(xyz, cent);
    ballq_kernel<<<(BATCH * MCENT) / 4, 256, 0, stream>>>(xyz, cent, grouped);
}